// Round 2
// baseline (346.093 us; speedup 1.0000x reference)
//
#include <hip/hip_runtime.h>
#include <math.h>

#define BATCH 8
#define CCH   256
#define TT    32
#define HWSZ  784      // 28*28
#define HID   512
#define EMB   32
#define KBINS 4
#define SCALEF 5.0f
#define EPSN  1e-12f

// ---------------------------------------------------------------------------
// Kernel 1 (fused pool+fc1+fc2): one block per (b,t), 512 threads = 8 waves.
// Pool: each wave reduces 32 channel-rows (2 per iteration -> ~6KB loads in
// flight per wave; 8 waves/CU -> ~48KB/CU, 2x Little's-law need at 6.3TB/s).
// Channel means live in LDS only -- no pooled[] global round-trip.
// fc1: thread per hidden unit, float4 global + float4 LDS dot-256, hswish.
// fc2: 16 threads per e, dot-512, shuffle reduce.
// ---------------------------------------------------------------------------
__global__ __launch_bounds__(512) void poolfc_kernel(
        const float* __restrict__ x,
        const float* __restrict__ W1, const float* __restrict__ b1,
        const float* __restrict__ W2, const float* __restrict__ b2,
        float* __restrict__ embds) {
    __shared__ float pc[CCH];
    __shared__ float hcol[HID];

    const int b    = blockIdx.x >> 5;
    const int t    = blockIdx.x & 31;
    const int tid  = threadIdx.x;
    const int wave = tid >> 6;               // 0..7
    const int lane = tid & 63;

    // ---- pool: channel means for this (b,t) into pc[] ---------------------
    const float* xbt = x + (size_t)(b * CCH) * (TT * HWSZ) + (size_t)t * HWSZ;
#pragma unroll
    for (int i = 0; i < 16; ++i) {
        const int c0 = (i << 4) + wave;      // two rows per iteration
        const int c1 = c0 + 8;
        const float4* xp0 = (const float4*)(xbt + (size_t)c0 * (TT * HWSZ));
        const float4* xp1 = (const float4*)(xbt + (size_t)c1 * (TT * HWSZ));
        float4 a0 = xp0[lane];
        float4 a1 = xp0[lane + 64];
        float4 a2 = xp0[lane + 128];
        float4 d0 = xp1[lane];
        float4 d1 = xp1[lane + 64];
        float4 d2 = xp1[lane + 128];
        float s0 = a0.x + a0.y + a0.z + a0.w
                 + a1.x + a1.y + a1.z + a1.w
                 + a2.x + a2.y + a2.z + a2.w;
        float s1 = d0.x + d0.y + d0.z + d0.w
                 + d1.x + d1.y + d1.z + d1.w
                 + d2.x + d2.y + d2.z + d2.w;
        if (lane < 4) {                      // tail: elements 768..783
            float4 a3 = xp0[lane + 192];
            float4 d3 = xp1[lane + 192];
            s0 += a3.x + a3.y + a3.z + a3.w;
            s1 += d3.x + d3.y + d3.z + d3.w;
        }
#pragma unroll
        for (int off = 32; off > 0; off >>= 1) {
            s0 += __shfl_down(s0, off);
            s1 += __shfl_down(s1, off);
        }
        if (lane == 0) {
            pc[c0] = s0 * (1.0f / 784.0f);
            pc[c1] = s1 * (1.0f / 784.0f);
        }
    }
    __syncthreads();

    // ---- fc1 + hswish -----------------------------------------------------
    {
        const float4* w = (const float4*)(W1 + (size_t)tid * CCH);
        const float4* p4 = (const float4*)pc;
        float acc = 0.f;
#pragma unroll 8
        for (int j = 0; j < CCH / 4; ++j) {
            float4 wv = w[j];
            float4 pv = p4[j];
            acc += wv.x * pv.x + wv.y * pv.y + wv.z * pv.z + wv.w * pv.w;
        }
        acc += b1[tid];
        float r = fminf(fmaxf(acc + 3.0f, 0.0f), 6.0f);
        hcol[tid] = acc * r * (1.0f / 6.0f);
    }
    __syncthreads();

    // ---- fc2: 16 threads per embedding dim --------------------------------
    {
        const int e = tid >> 4;              // 0..31
        const int l = tid & 15;
        const float* w = W2 + (size_t)e * HID;
        float acc = 0.f;
#pragma unroll
        for (int j = 0; j < HID / 16; j++) acc += w[l + 16 * j] * hcol[l + 16 * j];
        acc += __shfl_down(acc, 8);
        acc += __shfl_down(acc, 4);
        acc += __shfl_down(acc, 2);
        acc += __shfl_down(acc, 1);
        if (l == 0) embds[((size_t)b * EMB + e) * TT + t] = acc + b2[e];
    }
}

// ---------------------------------------------------------------------------
// Kernel 2: one block per batch — fully parallel middle. (proven baseline)
// ---------------------------------------------------------------------------
__global__ void group_kernel(const float* __restrict__ embds, float* __restrict__ nw) {
    __shared__ float se[EMB][TT + 1];
    __shared__ float ns[TT];
    __shared__ float colinv[TT];
    __shared__ float thr_sh;
    __shared__ float cs[EMB][KBINS];
    __shared__ float wts[TT][KBINS];
    __shared__ float gsize[KBINS];
    __shared__ float kfac[KBINS];
    __shared__ int   gid[TT];

    const int b   = blockIdx.x;
    const int tid = threadIdx.x;

    for (int i = tid; i < EMB * TT; i += 256)
        se[i >> 5][i & 31] = embds[(size_t)b * EMB * TT + i];
    __syncthreads();

    if (tid < TT) {
        float s = 0.f;
        for (int e = 0; e < EMB; e++) { float v = se[e][tid]; s += v * v; }
        colinv[tid] = 1.0f / fmaxf(sqrtf(s), EPSN);
    }
    __syncthreads();
    for (int i = tid; i < EMB * TT; i += 256) {
        int e = i >> 5, t = i & 31;
        se[e][t] *= colinv[t];
    }
    __syncthreads();

    if (tid < TT - 1) {
        float s = 0.f;
        for (int e = 0; e < EMB; e++) s += se[e][tid] * se[e][tid + 1];
        ns[tid] = s;
    }
    __syncthreads();

    // threshold = stable-rank-2 element (3rd smallest incl. duplicates)
    if (tid < TT - 1) {
        float v = ns[tid];
        int pos = 0;
        for (int j = 0; j < TT - 1; j++) {
            float u = ns[j];
            pos += (u < v) || (u == v && j < tid);
        }
        if (pos == KBINS - 2) thr_sh = v;
    }
    __syncthreads();

    if (tid < TT) {
        float thr = thr_sh;
        int g = 0;
        for (int s = 1; s <= tid; s++) g += !(ns[s - 1] > thr);
        gid[tid] = g;
    }
    __syncthreads();
    if (tid < KBINS) {
        float c = 0.f;
        for (int t = 0; t < TT; t++) c += (gid[t] == tid);
        gsize[tid] = c;
    }
    __syncthreads();

    if (tid < EMB * KBINS) {
        int e = tid >> 2, k = tid & 3;
        float s = 0.f;
        for (int t = 0; t < TT; t++) if (gid[t] == k) s += se[e][t];
        cs[e][k] = s / gsize[k];
    }
    __syncthreads();
    if (tid < KBINS) {
        float s = 0.f;
        for (int e = 0; e < EMB; e++) { float v = cs[e][tid]; s += v * v; }
        kfac[tid] = 1.0f / fmaxf(sqrtf(s), EPSN);
    }
    __syncthreads();
    if (tid < EMB * KBINS) {
        int e = tid >> 2, k = tid & 3;
        cs[e][k] *= kfac[k];
    }
    __syncthreads();

    if (tid < TT * KBINS) {
        int t = tid >> 2, k = tid & 3;
        float s = 0.f;
        for (int e = 0; e < EMB; e++) s += se[e][t] * cs[e][k];
        wts[t][k] = s * SCALEF;
    }
    __syncthreads();
    if (tid < TT) {
        float m = wts[tid][0];
        for (int k = 1; k < KBINS; k++) m = fmaxf(m, wts[tid][k]);
        float ex[KBINS]; float sum = 0.f;
        for (int k = 0; k < KBINS; k++) { ex[k] = expf(wts[tid][k] - m); sum += ex[k]; }
        float inv = 1.0f / sum;
        for (int k = 0; k < KBINS; k++) wts[tid][k] = ex[k] * inv;
    }
    __syncthreads();
    if (tid < KBINS) {
        float s = 0.f;
        for (int t = 0; t < TT; t++) s += wts[t][tid];
        kfac[tid] = (s > 0.f) ? (1.0f / s) : 1.0f;
    }
    __syncthreads();
    if (tid < TT * KBINS) {
        int t = tid >> 2, k = tid & 3;
        nw[((size_t)b * TT + t) * KBINS + k] = wts[t][k] * kfac[k];
    }
}

// ---------------------------------------------------------------------------
// Kernel 3: out[b,c,k,hw4] = sum_t x[b,c,t,hw4] * nw[b,t,k]  (proven baseline)
// ---------------------------------------------------------------------------
__global__ __launch_bounds__(128) void out_kernel(
        const float* __restrict__ x, const float* __restrict__ nw,
        float* __restrict__ out) {
    __shared__ float w[TT * KBINS];
    const int b = blockIdx.x / 392;
    const unsigned idx = (blockIdx.x % 392) * 128 + threadIdx.x;   // [0, 50176)
    w[threadIdx.x] = nw[(size_t)b * TT * KBINS + threadIdx.x];
    __syncthreads();
    const unsigned c = idx / 196;
    const unsigned f = idx % 196;
    const float4* xp = (const float4*)(x + ((size_t)(b * CCH + c) * TT) * HWSZ);
    float4 acc[KBINS];
#pragma unroll
    for (int k = 0; k < KBINS; k++) { acc[k].x = 0.f; acc[k].y = 0.f; acc[k].z = 0.f; acc[k].w = 0.f; }
#pragma unroll 8
    for (int t = 0; t < TT; t++) {
        float4 v = xp[t * 196 + f];
#pragma unroll
        for (int k = 0; k < KBINS; k++) {
            float wk = w[t * KBINS + k];
            acc[k].x += v.x * wk;
            acc[k].y += v.y * wk;
            acc[k].z += v.z * wk;
            acc[k].w += v.w * wk;
        }
    }
    float4* op = (float4*)(out + ((size_t)(b * CCH + c) * KBINS) * HWSZ);
#pragma unroll
    for (int k = 0; k < KBINS; k++) op[k * 196 + f] = acc[k];
}

extern "C" void kernel_launch(void* const* d_in, const int* in_sizes, int n_in,
                              void* d_out, int out_size, void* d_ws, size_t ws_size,
                              hipStream_t stream) {
    const float* x  = (const float*)d_in[0];
    const float* W1 = (const float*)d_in[1];
    const float* b1 = (const float*)d_in[2];
    const float* W2 = (const float*)d_in[3];
    const float* b2 = (const float*)d_in[4];
    float* out = (float*)d_out;

    float* ws    = (float*)d_ws;
    float* embds = ws;                           // B*EMB*T = 8192
    float* nw    = embds + BATCH * EMB * TT;     // B*T*K   = 1024

    poolfc_kernel<<<BATCH * TT, 512, 0, stream>>>(x, W1, b1, W2, b2, embds);
    group_kernel<<<BATCH, 256, 0, stream>>>(embds, nw);
    out_kernel<<<BATCH * 392, 128, 0, stream>>>(x, nw, out);
}

// Round 4
// 343.114 us; speedup vs baseline: 1.0087x; 1.0087x over previous
//
#include <hip/hip_runtime.h>
#include <math.h>

#define BATCH 8
#define CCH   256
#define TT    32
#define HWSZ  784      // 28*28
#define HID   512
#define EMB   32
#define KBINS 4
#define SCALEF 5.0f
#define EPSN  1e-12f

// ---------------------------------------------------------------------------
// Kernel 1 (fused pool+fc1+fc2): one block per (b,t), 512 threads = 8 waves.
// PROVEN in R2 (passed, 346 us total). Kept verbatim.
// ---------------------------------------------------------------------------
__global__ __launch_bounds__(512) void poolfc_kernel(
        const float* __restrict__ x,
        const float* __restrict__ W1, const float* __restrict__ b1,
        const float* __restrict__ W2, const float* __restrict__ b2,
        float* __restrict__ embds) {
    __shared__ float pc[CCH];
    __shared__ float hcol[HID];

    const int b    = blockIdx.x >> 5;
    const int t    = blockIdx.x & 31;
    const int tid  = threadIdx.x;
    const int wave = tid >> 6;               // 0..7
    const int lane = tid & 63;

    // ---- pool: channel means for this (b,t) into pc[] ---------------------
    const float* xbt = x + (size_t)(b * CCH) * (TT * HWSZ) + (size_t)t * HWSZ;
#pragma unroll
    for (int i = 0; i < 16; ++i) {
        const int c0 = (i << 4) + wave;      // two rows per iteration
        const int c1 = c0 + 8;
        const float4* xp0 = (const float4*)(xbt + (size_t)c0 * (TT * HWSZ));
        const float4* xp1 = (const float4*)(xbt + (size_t)c1 * (TT * HWSZ));
        float4 a0 = xp0[lane];
        float4 a1 = xp0[lane + 64];
        float4 a2 = xp0[lane + 128];
        float4 d0 = xp1[lane];
        float4 d1 = xp1[lane + 64];
        float4 d2 = xp1[lane + 128];
        float s0 = a0.x + a0.y + a0.z + a0.w
                 + a1.x + a1.y + a1.z + a1.w
                 + a2.x + a2.y + a2.z + a2.w;
        float s1 = d0.x + d0.y + d0.z + d0.w
                 + d1.x + d1.y + d1.z + d1.w
                 + d2.x + d2.y + d2.z + d2.w;
        if (lane < 4) {                      // tail: elements 768..783
            float4 a3 = xp0[lane + 192];
            float4 d3 = xp1[lane + 192];
            s0 += a3.x + a3.y + a3.z + a3.w;
            s1 += d3.x + d3.y + d3.z + d3.w;
        }
#pragma unroll
        for (int off = 32; off > 0; off >>= 1) {
            s0 += __shfl_down(s0, off);
            s1 += __shfl_down(s1, off);
        }
        if (lane == 0) {
            pc[c0] = s0 * (1.0f / 784.0f);
            pc[c1] = s1 * (1.0f / 784.0f);
        }
    }
    __syncthreads();

    // ---- fc1 + hswish -----------------------------------------------------
    {
        const float4* w = (const float4*)(W1 + (size_t)tid * CCH);
        const float4* p4 = (const float4*)pc;
        float acc = 0.f;
#pragma unroll 8
        for (int j = 0; j < CCH / 4; ++j) {
            float4 wv = w[j];
            float4 pv = p4[j];
            acc += wv.x * pv.x + wv.y * pv.y + wv.z * pv.z + wv.w * pv.w;
        }
        acc += b1[tid];
        float r = fminf(fmaxf(acc + 3.0f, 0.0f), 6.0f);
        hcol[tid] = acc * r * (1.0f / 6.0f);
    }
    __syncthreads();

    // ---- fc2: 16 threads per embedding dim --------------------------------
    {
        const int e = tid >> 4;              // 0..31
        const int l = tid & 15;
        const float* w = W2 + (size_t)e * HID;
        float acc = 0.f;
#pragma unroll
        for (int j = 0; j < HID / 16; j++) acc += w[l + 16 * j] * hcol[l + 16 * j];
        acc += __shfl_down(acc, 8);
        acc += __shfl_down(acc, 4);
        acc += __shfl_down(acc, 2);
        acc += __shfl_down(acc, 1);
        if (l == 0) embds[((size_t)b * EMB + e) * TT + t] = acc + b2[e];
    }
}

// ---------------------------------------------------------------------------
// Kernel 2 (group+out fused): 1568 blocks x 256 threads; b = blockIdx/196.
// Preamble: every block REDUNDANTLY recomputes its batch's weight table from
// embds (8 KB, L2-hot; deterministic -> identical in all blocks). Removes the
// separate group dispatch, its grid-drain boundary, and the nw round-trip.
// Pure kernel launches only — no atomics/memset/cooperative (graph-safe).
// Main loop: out[b,c,k,hw4] = sum_t x[b,c,t,hw4] * wl[t][k]; weight table
// read as float4 (ds_read_b128 per t); x re-read is L3-resident.
// ---------------------------------------------------------------------------
__global__ __launch_bounds__(256) void outg_kernel(
        const float* __restrict__ x, const float* __restrict__ embds,
        float* __restrict__ out) {
    __shared__ float se[EMB][TT + 1];
    __shared__ float ns[TT];
    __shared__ float colinv[TT];
    __shared__ float thr_sh;
    __shared__ float cs[EMB][KBINS];
    __shared__ float wts[TT][KBINS];
    __shared__ float gsize[KBINS];
    __shared__ float kfac[KBINS];
    __shared__ int   gid[TT];
    __shared__ float wl[TT * KBINS];

    const int b   = blockIdx.x / 196;
    const int tid = threadIdx.x;

    // ==== group preamble (identical math to proven group_kernel) ====
    for (int i = tid; i < EMB * TT; i += 256)
        se[i >> 5][i & 31] = embds[(size_t)b * EMB * TT + i];
    __syncthreads();

    if (tid < TT) {
        float s = 0.f;
        for (int e = 0; e < EMB; e++) { float v = se[e][tid]; s += v * v; }
        colinv[tid] = 1.0f / fmaxf(sqrtf(s), EPSN);
    }
    __syncthreads();
    for (int i = tid; i < EMB * TT; i += 256) {
        int e = i >> 5, t = i & 31;
        se[e][t] *= colinv[t];
    }
    __syncthreads();

    if (tid < TT - 1) {
        float s = 0.f;
        for (int e = 0; e < EMB; e++) s += se[e][tid] * se[e][tid + 1];
        ns[tid] = s;
    }
    __syncthreads();

    // threshold = stable-rank-2 element (3rd smallest incl. duplicates)
    if (tid < TT - 1) {
        float v = ns[tid];
        int pos = 0;
        for (int j = 0; j < TT - 1; j++) {
            float u = ns[j];
            pos += (u < v) || (u == v && j < tid);
        }
        if (pos == KBINS - 2) thr_sh = v;
    }
    __syncthreads();

    if (tid < TT) {
        float thr = thr_sh;
        int g = 0;
        for (int s = 1; s <= tid; s++) g += !(ns[s - 1] > thr);
        gid[tid] = g;
    }
    __syncthreads();
    if (tid < KBINS) {
        float c = 0.f;
        for (int t = 0; t < TT; t++) c += (gid[t] == tid);
        gsize[tid] = c;
    }
    __syncthreads();

    if (tid < EMB * KBINS) {
        int e = tid >> 2, k = tid & 3;
        float s = 0.f;
        for (int t = 0; t < TT; t++) if (gid[t] == k) s += se[e][t];
        cs[e][k] = s / gsize[k];
    }
    __syncthreads();
    if (tid < KBINS) {
        float s = 0.f;
        for (int e = 0; e < EMB; e++) { float v = cs[e][tid]; s += v * v; }
        kfac[tid] = 1.0f / fmaxf(sqrtf(s), EPSN);
    }
    __syncthreads();
    if (tid < EMB * KBINS) {
        int e = tid >> 2, k = tid & 3;
        cs[e][k] *= kfac[k];
    }
    __syncthreads();

    if (tid < TT * KBINS) {
        int t = tid >> 2, k = tid & 3;
        float s = 0.f;
        for (int e = 0; e < EMB; e++) s += se[e][t] * cs[e][k];
        wts[t][k] = s * SCALEF;
    }
    __syncthreads();
    if (tid < TT) {
        float m = wts[tid][0];
        for (int k = 1; k < KBINS; k++) m = fmaxf(m, wts[tid][k]);
        float ex[KBINS]; float sum = 0.f;
        for (int k = 0; k < KBINS; k++) { ex[k] = expf(wts[tid][k] - m); sum += ex[k]; }
        float inv = 1.0f / sum;
        for (int k = 0; k < KBINS; k++) wts[tid][k] = ex[k] * inv;
    }
    __syncthreads();
    if (tid < KBINS) {
        float s = 0.f;
        for (int t = 0; t < TT; t++) s += wts[t][tid];
        kfac[tid] = (s > 0.f) ? (1.0f / s) : 1.0f;
    }
    __syncthreads();
    if (tid < TT * KBINS) {
        int t = tid >> 2, k = tid & 3;
        wl[tid] = wts[t][k] * kfac[k];       // [t][k] layout -> float4 per t
    }
    __syncthreads();

    // ==== weighted-sum main loop ====
    const unsigned idx = (blockIdx.x % 196) * 256 + tid;   // [0, 50176)
    const unsigned c = idx / 196;
    const unsigned f = idx % 196;
    const float4* xp = (const float4*)(x + ((size_t)(b * CCH + c) * TT) * HWSZ);
    const float4* wp = (const float4*)wl;                  // wp[t] = (k0..k3)
    float4 a0 = {0.f, 0.f, 0.f, 0.f};
    float4 a1 = {0.f, 0.f, 0.f, 0.f};
    float4 a2 = {0.f, 0.f, 0.f, 0.f};
    float4 a3 = {0.f, 0.f, 0.f, 0.f};
#pragma unroll 8
    for (int t = 0; t < TT; ++t) {
        float4 v  = xp[t * 196 + f];
        float4 wv = wp[t];
        a0.x += v.x * wv.x; a0.y += v.y * wv.x; a0.z += v.z * wv.x; a0.w += v.w * wv.x;
        a1.x += v.x * wv.y; a1.y += v.y * wv.y; a1.z += v.z * wv.y; a1.w += v.w * wv.y;
        a2.x += v.x * wv.z; a2.y += v.y * wv.z; a2.z += v.z * wv.z; a2.w += v.w * wv.z;
        a3.x += v.x * wv.w; a3.y += v.y * wv.w; a3.z += v.z * wv.w; a3.w += v.w * wv.w;
    }
    float4* op = (float4*)(out + ((size_t)(b * CCH + c) * KBINS) * HWSZ);
    op[0 * 196 + f] = a0;
    op[1 * 196 + f] = a1;
    op[2 * 196 + f] = a2;
    op[3 * 196 + f] = a3;
}

extern "C" void kernel_launch(void* const* d_in, const int* in_sizes, int n_in,
                              void* d_out, int out_size, void* d_ws, size_t ws_size,
                              hipStream_t stream) {
    const float* x  = (const float*)d_in[0];
    const float* W1 = (const float*)d_in[1];
    const float* b1 = (const float*)d_in[2];
    const float* W2 = (const float*)d_in[3];
    const float* b2 = (const float*)d_in[4];
    float* out = (float*)d_out;

    float* embds = (float*)d_ws;                 // B*EMB*T = 8192

    poolfc_kernel<<<BATCH * TT, 512, 0, stream>>>(x, W1, b1, W2, b2, embds);
    outg_kernel<<<BATCH * 196, 256, 0, stream>>>(x, embds, out);
}